// Round 5
// baseline (9955.288 us; speedup 1.0000x reference)
//
#include <hip/hip_runtime.h>
#include <cmath>

#define U_N 200000
#define L_N 20000
#define T_N 48
#define A_N 2000

// packed CSR entry: (col << 14) | round(val * 2^20)   [val in [0,0.01) => <= 10486]
#define VAL_SCALE_INV 9.5367431640625e-7f   // 2^-20

struct MatB {
    const int* r; const int* c; const float* v;
    int nnz; int nrows;
    int* rp; int* cur; unsigned* pk;
};
struct AllMats { MatB m[10]; };

__device__ __forceinline__ unsigned short f2bf(float f) {
    unsigned u = __float_as_uint(f);
    return (unsigned short)((u + 0x7FFFu + ((u >> 16) & 1u)) >> 16);
}
__device__ __forceinline__ float bf2f(unsigned short us) {
    return __uint_as_float(((unsigned)us) << 16);
}
// decode entry e, gather x[col][lane], return val*x
__device__ __forceinline__ float gfma(const unsigned short* __restrict__ x, unsigned e, int lane) {
    unsigned col = e >> 14;
    float xv = bf2f(x[((size_t)col << 5) + lane]);
    return xv * ((float)(e & 16383u) * VAL_SCALE_INV);
}

// =====================================================================
// init / finalize
// =====================================================================
__global__ void k_init_users(const float* __restrict__ ue,
                             unsigned short* __restrict__ u_l, unsigned short* __restrict__ u_t,
                             unsigned short* __restrict__ u_a, float* __restrict__ out_users) {
    int i = blockIdx.x * blockDim.x + threadIdx.x;
    if (i >= U_N * 96) return;
    float v = ue[i];
    out_users[i] = v;
    int u = i / 96;
    int d = i - u * 96;
    unsigned short b = f2bf(v);
    if (d < 32)       u_l[u * 32 + d]      = b;
    else if (d < 64)  u_t[u * 32 + d - 32] = b;
    else              u_a[u * 32 + d - 64] = b;
}

__global__ void k_scale(float* __restrict__ out, int n) {
    int i = blockIdx.x * blockDim.x + threadIdx.x;
    if (i < n) out[i] *= (1.0f / 3.0f);
}

// =====================================================================
// batched CSR build over all 10 matrices (blockIdx.y = matrix id)
// =====================================================================
__global__ void k_hist_all(AllMats A) {
    const MatB mm = A.m[blockIdx.y];
    int i = blockIdx.x * blockDim.x + threadIdx.x;
    if (i < mm.nnz) atomicAdd(&mm.rp[mm.r[i]], 1);
}

__global__ void k_block_sums_all(AllMats A, int* __restrict__ bsum_all) {
    const MatB mm = A.m[blockIdx.y];
    int* bsum = bsum_all + blockIdx.y * 256;
    int n = mm.nrows;
    int t = threadIdx.x;
    int g0 = blockIdx.x * 1024 + t * 4;
    int s = 0;
#pragma unroll
    for (int k = 0; k < 4; ++k) if (g0 + k < n) s += mm.rp[g0 + k];
#pragma unroll
    for (int off = 32; off; off >>= 1) s += __shfl_down(s, off, 64);
    __shared__ int ws_[4];
    if ((t & 63) == 0) ws_[t >> 6] = s;
    __syncthreads();
    if (t == 0) bsum[blockIdx.x] = ws_[0] + ws_[1] + ws_[2] + ws_[3];
}

__global__ void k_scan_bsums_all(AllMats A, int* __restrict__ bsum_all) {
    const MatB mm = A.m[blockIdx.y];
    int* bsum = bsum_all + blockIdx.y * 256;
    int nblk = (mm.nrows + 1023) / 1024;
    __shared__ int s[256];
    int t = threadIdx.x;
    int v = (t < nblk) ? bsum[t] : 0;
    s[t] = v;
    __syncthreads();
    for (int off = 1; off < 256; off <<= 1) {
        int x = (t >= off) ? s[t - off] : 0;
        __syncthreads();
        s[t] += x;
        __syncthreads();
    }
    if (t < nblk) bsum[t] = s[t] - v;
    if (t == 255) mm.rp[mm.nrows] = s[255];
}

__global__ void k_scan_chunk_all(AllMats A, const int* __restrict__ bsum_all) {
    const MatB mm = A.m[blockIdx.y];
    const int* bsum = bsum_all + blockIdx.y * 256;
    int n = mm.nrows;
    int t = threadIdx.x;
    int g0 = blockIdx.x * 1024 + t * 4;
    int v0 = 0, v1 = 0, v2 = 0, v3 = 0;
    if (g0 + 0 < n) v0 = mm.rp[g0 + 0];
    if (g0 + 1 < n) v1 = mm.rp[g0 + 1];
    if (g0 + 2 < n) v2 = mm.rp[g0 + 2];
    if (g0 + 3 < n) v3 = mm.rp[g0 + 3];
    int local = v0 + v1 + v2 + v3;
    int lane = t & 63, w = t >> 6;
    int inc = local;
#pragma unroll
    for (int off = 1; off < 64; off <<= 1) {
        int o = __shfl_up(inc, off, 64);
        if (lane >= off) inc += o;
    }
    __shared__ int wsum[4];
    if (lane == 63) wsum[w] = inc;
    __syncthreads();
    int wbase = 0;
    for (int i = 0; i < w; ++i) wbase += wsum[i];
    int run = bsum[blockIdx.x] + wbase + (inc - local);
    if (g0 + 0 < n) { mm.rp[g0 + 0] = run; mm.cur[g0 + 0] = run; run += v0; }
    if (g0 + 1 < n) { mm.rp[g0 + 1] = run; mm.cur[g0 + 1] = run; run += v1; }
    if (g0 + 2 < n) { mm.rp[g0 + 2] = run; mm.cur[g0 + 2] = run; run += v2; }
    if (g0 + 3 < n) { mm.rp[g0 + 3] = run; mm.cur[g0 + 3] = run; run += v3; }
}

__global__ void k_scatter_all(AllMats A) {
    const MatB mm = A.m[blockIdx.y];
    int i = blockIdx.x * blockDim.x + threadIdx.x;
    if (i >= mm.nnz) return;
    int r = mm.r[i];
    int p = atomicAdd(&mm.cur[r], 1);
    unsigned col = (unsigned)mm.c[i];
    unsigned q = (unsigned)(mm.v[i] * 1048576.0f + 0.5f);
    if (q > 16383u) q = 16383u;
    mm.pk[p] = (col << 14) | q;
}

// =====================================================================
// mega: 4 packed-CSR row-sums + attention fusion; one user per 32-lane group
// =====================================================================
__global__ void k_mega(const int* __restrict__ rp0, const unsigned* __restrict__ pk0,
                       const int* __restrict__ rp1, const unsigned* __restrict__ pk1,
                       const int* __restrict__ rp2, const unsigned* __restrict__ pk2,
                       const int* __restrict__ rp3, const unsigned* __restrict__ pk3,
                       const unsigned short* __restrict__ x,
                       const float* __restrict__ W1, const float* __restrict__ b1,
                       const float* __restrict__ w2,
                       unsigned short* __restrict__ u_out, float* __restrict__ out_users, int f) {
    __shared__ float sW[32 * 32];
    __shared__ float sb[32];
    __shared__ float sw2[32];
    for (int i = threadIdx.x; i < 1024; i += blockDim.x) sW[i] = W1[i];
    if (threadIdx.x < 32) { sb[threadIdx.x] = b1[threadIdx.x]; sw2[threadIdx.x] = w2[threadIdx.x]; }
    __syncthreads();

    int grp = threadIdx.x >> 5;
    int lane = threadIdx.x & 31;
    int r = blockIdx.x * 8 + grp;
    if (r >= U_N) return;

    const int*      rps[4] = {rp0, rp1, rp2, rp3};
    const unsigned* pks[4] = {pk0, pk1, pk2, pk3};
    float zk[4];
#pragma unroll 1
    for (int ch = 0; ch < 4; ++ch) {
        const int* rp = rps[ch];
        const unsigned* pk = pks[ch];
        int j = rp[r], end = rp[r + 1];
        float a = 0.f;
        for (; j + 8 <= end; j += 8) {
            unsigned e0 = pk[j],     e1 = pk[j + 1], e2 = pk[j + 2], e3 = pk[j + 3];
            unsigned e4 = pk[j + 4], e5 = pk[j + 5], e6 = pk[j + 6], e7 = pk[j + 7];
            a += gfma(x, e0, lane); a += gfma(x, e1, lane);
            a += gfma(x, e2, lane); a += gfma(x, e3, lane);
            a += gfma(x, e4, lane); a += gfma(x, e5, lane);
            a += gfma(x, e6, lane); a += gfma(x, e7, lane);
        }
        for (; j + 4 <= end; j += 4) {
            unsigned e0 = pk[j], e1 = pk[j + 1], e2 = pk[j + 2], e3 = pk[j + 3];
            a += gfma(x, e0, lane); a += gfma(x, e1, lane);
            a += gfma(x, e2, lane); a += gfma(x, e3, lane);
        }
        for (; j < end; ++j) a += gfma(x, pk[j], lane);
        zk[ch] = a;
    }

    float w[4];
#pragma unroll
    for (int k = 0; k < 4; ++k) {
        float h = sb[lane];
#pragma unroll
        for (int i = 0; i < 32; ++i) {
            float zi = __shfl(zk[k], i, 32);
            h += zi * sW[i * 32 + lane];
        }
        float p = tanhf(h) * sw2[lane];
#pragma unroll
        for (int off = 16; off; off >>= 1) p += __shfl_xor(p, off, 32);
        w[k] = p;
    }
    float m = fmaxf(fmaxf(w[0], w[1]), fmaxf(w[2], w[3]));
    float e0 = __expf(w[0] - m), e1 = __expf(w[1] - m), e2 = __expf(w[2] - m), e3 = __expf(w[3] - m);
    float inv = 1.f / (e0 + e1 + e2 + e3);
    float o = (e0 * zk[0] + e1 * zk[1] + e2 * zk[2] + e3 * zk[3]) * inv;
    u_out[(size_t)r * 32 + lane] = f2bf(o);
    out_users[(size_t)r * 96 + f * 32 + lane] += o;
}

// =====================================================================
// vtoe: packed-CSR split pull, atomicAdd into out (out pre-seeded)
// =====================================================================
__global__ void k_vtoe_split(const int* __restrict__ rp, const unsigned* __restrict__ pk,
                             const unsigned short* __restrict__ x, float* __restrict__ out,
                             int n_rows, int S) {
    int gid = (blockIdx.x * blockDim.x + threadIdx.x) >> 5;
    int lane = threadIdx.x & 31;
    if (gid >= n_rows * S) return;
    int r = gid / S, s = gid - r * S;
    int beg = rp[r], end = rp[r + 1], len = end - beg;
    int chunk = (len + S - 1) / S;
    int b = beg + s * chunk;
    int e = min(end, b + chunk);
    if (b >= e) return;
    float a = 0.f;
    int j = b;
    for (; j + 4 <= e; j += 4) {
        unsigned t0 = pk[j], t1 = pk[j + 1], t2 = pk[j + 2], t3 = pk[j + 3];
        a += gfma(x, t0, lane); a += gfma(x, t1, lane);
        a += gfma(x, t2, lane); a += gfma(x, t3, lane);
    }
    for (; j < e; ++j) a += gfma(x, pk[j], lane);
    atomicAdd(&out[(size_t)r * 32 + lane], a);
}

// =====================================================================
// fallback (atomic z) kernels — only used if ws is unexpectedly small
// =====================================================================
__global__ void k_init_users_f32(const float* __restrict__ ue,
                                 float* __restrict__ u_l, float* __restrict__ u_t,
                                 float* __restrict__ u_a, float* __restrict__ out_users) {
    int i = blockIdx.x * blockDim.x + threadIdx.x;
    if (i >= U_N * 96) return;
    float v = ue[i];
    out_users[i] = v;
    int u = i / 96;
    int d = i - u * 96;
    if (d < 32)       u_l[u * 32 + d]      = v;
    else if (d < 64)  u_t[u * 32 + d - 32] = v;
    else              u_a[u * 32 + d - 64] = v;
}

__global__ void k_spmm(const int* __restrict__ rows, const int* __restrict__ cols,
                       const float* __restrict__ vals, int nnz,
                       const float* __restrict__ x, float* __restrict__ y) {
    int tid = blockIdx.x * blockDim.x + threadIdx.x;
    int nz = tid >> 5;
    if (nz >= nnz) return;
    int d = tid & 31;
    atomicAdd(&y[(size_t)rows[nz] * 32 + d], vals[nz] * x[(size_t)cols[nz] * 32 + d]);
}

__global__ void k_spmm_smallT(const int* __restrict__ rows, const int* __restrict__ cols,
                              const float* __restrict__ vals, int nnz,
                              const float* __restrict__ x, float* __restrict__ y) {
    __shared__ float acc[T_N * 32];
    for (int i = threadIdx.x; i < T_N * 32; i += blockDim.x) acc[i] = 0.f;
    __syncthreads();
    int d = threadIdx.x & 31;
    int grp = threadIdx.x >> 5;
    int per_block = (nnz + gridDim.x - 1) / gridDim.x;
    int start = blockIdx.x * per_block;
    int end = min(nnz, start + per_block);
    for (int nz = start + grp; nz < end; nz += (blockDim.x >> 5))
        atomicAdd(&acc[rows[nz] * 32 + d], vals[nz] * x[(size_t)cols[nz] * 32 + d]);
    __syncthreads();
    for (int i = threadIdx.x; i < T_N * 32; i += blockDim.x)
        if (acc[i] != 0.f) atomicAdd(&y[i], acc[i]);
}

__global__ void k_attn(const float* __restrict__ z, const float* __restrict__ W1,
                       const float* __restrict__ b1, const float* __restrict__ w2,
                       float* __restrict__ u_out, float* __restrict__ out_users, int f) {
    __shared__ float sW[32 * 32];
    __shared__ float sb[32];
    __shared__ float sw2[32];
    for (int i = threadIdx.x; i < 1024; i += blockDim.x) sW[i] = W1[i];
    if (threadIdx.x < 32) { sb[threadIdx.x] = b1[threadIdx.x]; sw2[threadIdx.x] = w2[threadIdx.x]; }
    __syncthreads();
    int half = threadIdx.x >> 5;
    int j = threadIdx.x & 31;
    int u = blockIdx.x * 8 + half;
    if (u >= U_N) return;
    float zk[4];
#pragma unroll
    for (int k = 0; k < 4; ++k) zk[k] = z[(size_t)k * (U_N * 32) + (size_t)u * 32 + j];
    float w[4];
#pragma unroll
    for (int k = 0; k < 4; ++k) {
        float h = sb[j];
#pragma unroll
        for (int i = 0; i < 32; ++i) h += __shfl(zk[k], i, 32) * sW[i * 32 + j];
        float p = tanhf(h) * sw2[j];
#pragma unroll
        for (int off = 16; off; off >>= 1) p += __shfl_xor(p, off, 32);
        w[k] = p;
    }
    float m = fmaxf(fmaxf(w[0], w[1]), fmaxf(w[2], w[3]));
    float e0 = __expf(w[0] - m), e1 = __expf(w[1] - m), e2 = __expf(w[2] - m), e3 = __expf(w[3] - m);
    float inv = 1.f / (e0 + e1 + e2 + e3);
    float o = (e0 * zk[0] + e1 * zk[1] + e2 * zk[2] + e3 * zk[3]) * inv;
    u_out[(size_t)u * 32 + j] = o;
    out_users[(size_t)u * 96 + f * 32 + j] += o;
}

// =====================================================================
// host
// =====================================================================
extern "C" void kernel_launch(void* const* d_in, const int* in_sizes, int n_in,
                              void* d_out, int out_size, void* d_ws, size_t ws_size,
                              hipStream_t stream) {
    const float* user_emb = (const float*)d_in[0];
    const float* loc_emb  = (const float*)d_in[1];
    const float* time_emb = (const float*)d_in[2];
    const float* act_emb  = (const float*)d_in[3];
    const float* W1s[3] = {(const float*)d_in[4], (const float*)d_in[7], (const float*)d_in[10]};
    const float* b1s[3] = {(const float*)d_in[5], (const float*)d_in[8], (const float*)d_in[11]};
    const float* w2s[3] = {(const float*)d_in[6], (const float*)d_in[9], (const float*)d_in[12]};

    struct Mat { const int* r; const int* c; const float* v; int nnz; int nrows; };
    auto mk = [&](int base, int nrows) {
        return Mat{(const int*)d_in[base], (const int*)d_in[base + 1],
                   (const float*)d_in[base + 2], in_sizes[base], nrows};
    };
    // 0..6: L,T,A,LT,LA,TA,LTA (rows=U); 7: vtoeL; 8: vtoeT; 9: vtoeA
    Mat M[10] = {mk(13, U_N), mk(16, U_N), mk(19, U_N), mk(22, U_N), mk(25, U_N),
                 mk(28, U_N), mk(31, U_N), mk(34, L_N), mk(37, T_N), mk(40, A_N)};

    float* out       = (float*)d_out;
    float* out_users = out;
    float* out_l     = out + (size_t)U_N * 96;
    float* out_t     = out_l + (size_t)L_N * 32;
    float* out_a     = out_t + (size_t)T_N * 32;

    const int chmat[3][4] = {{0, 3, 4, 6}, {1, 3, 5, 6}, {2, 4, 5, 6}};

    // ------- workspace layout (all resident) -------
    auto align256 = [](size_t x) { return (x + 255) & ~(size_t)255; };
    char* wsb = (char*)d_ws;
    size_t off = 0;
    size_t ubuf_off[4];
    for (int b = 0; b < 4; ++b) { ubuf_off[b] = off; off = align256(off + (size_t)U_N * 32 * 2); }
    size_t rp_off[10], cur_off[10], pk_off[10];
    size_t rp_begin = off;
    for (int m = 0; m < 10; ++m) { rp_off[m] = off; off = align256(off + ((size_t)M[m].nrows + 1) * 4); }
    size_t rp_total = off - rp_begin;
    for (int m = 0; m < 10; ++m) { cur_off[m] = off; off = align256(off + ((size_t)M[m].nrows + 1) * 4); }
    size_t bs_off = off; off = align256(off + 10 * 256 * 4);
    for (int m = 0; m < 10; ++m) { pk_off[m] = off; off = align256(off + (size_t)M[m].nnz * 4); }
    size_t NEED = off;

    if (ws_size >= NEED) {
        // ======================= packed-CSR path =======================
        AllMats A;
        int max_nnz = 0, max_nrows = 0;
        for (int m = 0; m < 10; ++m) {
            A.m[m].r = M[m].r; A.m[m].c = M[m].c; A.m[m].v = M[m].v;
            A.m[m].nnz = M[m].nnz; A.m[m].nrows = M[m].nrows;
            A.m[m].rp  = (int*)(wsb + rp_off[m]);
            A.m[m].cur = (int*)(wsb + cur_off[m]);
            A.m[m].pk  = (unsigned*)(wsb + pk_off[m]);
            if (M[m].nnz > max_nnz) max_nnz = M[m].nnz;
            if (M[m].nrows > max_nrows) max_nrows = M[m].nrows;
        }
        int* bsum_all = (int*)(wsb + bs_off);

        hipMemsetAsync(wsb + rp_begin, 0, rp_total, stream);
        dim3 gh((max_nnz + 255) / 256, 10);
        dim3 gb((max_nrows + 1023) / 1024, 10);
        k_hist_all<<<gh, 256, 0, stream>>>(A);
        k_block_sums_all<<<gb, 256, 0, stream>>>(A, bsum_all);
        k_scan_bsums_all<<<dim3(1, 10), 256, 0, stream>>>(A, bsum_all);
        k_scan_chunk_all<<<gb, 256, 0, stream>>>(A, bsum_all);
        k_scatter_all<<<gh, 256, 0, stream>>>(A);

        // ---- init snapshots
        unsigned short* bufs[4];
        for (int b = 0; b < 4; ++b) bufs[b] = (unsigned short*)(wsb + ubuf_off[b]);
        unsigned short* ucur[3] = {bufs[0], bufs[1], bufs[2]};
        unsigned short* uspare = bufs[3];
        k_init_users<<<(U_N * 96 + 255) / 256, 256, 0, stream>>>(
            user_emb, ucur[0], ucur[1], ucur[2], out_users);
        hipMemcpyAsync(out_l, loc_emb,  (size_t)L_N * 32 * 4, hipMemcpyDeviceToDevice, stream);
        hipMemcpyAsync(out_t, time_emb, (size_t)T_N * 32 * 4, hipMemcpyDeviceToDevice, stream);
        hipMemcpyAsync(out_a, act_emb,  (size_t)A_N * 32 * 4, hipMemcpyDeviceToDevice, stream);

        float* oute[3] = {out_l, out_t, out_a};
        const int Svt[3] = {4, 1024, 16};

        for (int f = 0; f < 3; ++f) {
            const int* cm = chmat[f];
            int vm = 7 + f;
            int ngrp = M[vm].nrows * Svt[f];
            for (int layer = 0; layer < 2; ++layer) {
                // vertex->edge from pre-attention ucur[f]
                k_vtoe_split<<<((size_t)ngrp * 32 + 255) / 256, 256, 0, stream>>>(
                    A.m[vm].rp, A.m[vm].pk, ucur[f], oute[f], M[vm].nrows, Svt[f]);
                // fused 4-channel pull-spmm + attention
                k_mega<<<(U_N + 7) / 8, 256, 0, stream>>>(
                    A.m[cm[0]].rp, A.m[cm[0]].pk,
                    A.m[cm[1]].rp, A.m[cm[1]].pk,
                    A.m[cm[2]].rp, A.m[cm[2]].pk,
                    A.m[cm[3]].rp, A.m[cm[3]].pk,
                    ucur[f], W1s[f], b1s[f], w2s[f], uspare, out_users, f);
                unsigned short* t = ucur[f]; ucur[f] = uspare; uspare = t;
            }
        }
    } else {
        // ======================= atomic fallback =======================
        float* ws = (float*)d_ws;
        float* z = ws;
        float* u[3];
        u[0] = ws + (size_t)4 * U_N * 32;
        u[1] = u[0] + (size_t)U_N * 32;
        u[2] = u[1] + (size_t)U_N * 32;
        k_init_users_f32<<<(U_N * 96 + 255) / 256, 256, 0, stream>>>(
            user_emb, u[0], u[1], u[2], out_users);
        hipMemcpyAsync(out_l, loc_emb,  (size_t)L_N * 32 * 4, hipMemcpyDeviceToDevice, stream);
        hipMemcpyAsync(out_t, time_emb, (size_t)T_N * 32 * 4, hipMemcpyDeviceToDevice, stream);
        hipMemcpyAsync(out_a, act_emb,  (size_t)A_N * 32 * 4, hipMemcpyDeviceToDevice, stream);
        float* oute[3] = {out_l, out_t, out_a};
        for (int layer = 0; layer < 2; ++layer) {
            for (int f = 0; f < 3; ++f) {
                hipMemsetAsync(z, 0, (size_t)4 * U_N * 32 * 4, stream);
                for (int k = 0; k < 4; ++k) {
                    Mat& m = M[chmat[f][k]];
                    k_spmm<<<((size_t)m.nnz * 32 + 255) / 256, 256, 0, stream>>>(
                        m.r, m.c, m.v, m.nnz, u[f], z + (size_t)k * U_N * 32);
                }
                Mat& vm = M[7 + f];
                if (f == 1)
                    k_spmm_smallT<<<2048, 256, 0, stream>>>(vm.r, vm.c, vm.v, vm.nnz, u[f], oute[f]);
                else
                    k_spmm<<<((size_t)vm.nnz * 32 + 255) / 256, 256, 0, stream>>>(
                        vm.r, vm.c, vm.v, vm.nnz, u[f], oute[f]);
                k_attn<<<(U_N + 7) / 8, 256, 0, stream>>>(z, W1s[f], b1s[f], w2s[f], u[f], out_users, f);
            }
        }
    }

    int total = U_N * 96 + L_N * 32 + T_N * 32 + A_N * 32;
    k_scale<<<(total + 255) / 256, 256, 0, stream>>>(out, total);
}

// Round 6
// 5840.347 us; speedup vs baseline: 1.7046x; 1.7046x over previous
//
#include <hip/hip_runtime.h>
#include <cmath>

#define U_N 200000
#define L_N 20000
#define T_N 48
#define A_N 2000

// packed CSR entry: (col << 14) | round(val * 2^20)   [val in [0,0.01) => <= 10486]
#define VAL_SCALE_INV 9.5367431640625e-7f   // 2^-20
#define BSHIFT 6                            // 64 rows per bucket (U-matrices)

struct MatB {
    const int* r; const int* c; const float* v;
    int nnz; int nrows;
    int* rp; int* cur; unsigned* pk;
};
struct Batch9 { MatB m[9]; };   // 0..6 = U-mats, 7 = vtoeL, 8 = vtoeA

__device__ __forceinline__ unsigned short f2bf(float f) {
    unsigned u = __float_as_uint(f);
    return (unsigned short)((u + 0x7FFFu + ((u >> 16) & 1u)) >> 16);
}
__device__ __forceinline__ float bf2f(unsigned short us) {
    return __uint_as_float(((unsigned)us) << 16);
}
__device__ __forceinline__ float gfma(const unsigned short* __restrict__ x, unsigned e, int lane) {
    unsigned col = e >> 14;
    float xv = bf2f(x[((size_t)col << 5) + lane]);
    return xv * ((float)(e & 16383u) * VAL_SCALE_INV);
}
__device__ __forceinline__ unsigned quant14(float v) {
    unsigned q = (unsigned)(v * 1048576.0f + 0.5f);
    return q > 16383u ? 16383u : q;
}

// =====================================================================
// init / finalize
// =====================================================================
__global__ void k_init_users(const float* __restrict__ ue,
                             unsigned short* __restrict__ u_l, unsigned short* __restrict__ u_t,
                             unsigned short* __restrict__ u_a, float* __restrict__ out_users) {
    int i = blockIdx.x * blockDim.x + threadIdx.x;
    if (i >= U_N * 96) return;
    float v = ue[i];
    out_users[i] = v;
    int u = i / 96;
    int d = i - u * 96;
    unsigned short b = f2bf(v);
    if (d < 32)       u_l[u * 32 + d]      = b;
    else if (d < 64)  u_t[u * 32 + d - 32] = b;
    else              u_a[u * 32 + d - 64] = b;
}

__global__ void k_scale(float* __restrict__ out, int n) {
    int i = blockIdx.x * blockDim.x + threadIdx.x;
    if (i < n) out[i] *= (1.0f / 3.0f);
}

// =====================================================================
// batched hist + scan over the 9 CSR-built matrices
// =====================================================================
__global__ void k_hist_all(Batch9 A) {
    const MatB mm = A.m[blockIdx.y];
    int i = blockIdx.x * blockDim.x + threadIdx.x;
    if (i < mm.nnz) atomicAdd(&mm.rp[mm.r[i]], 1);
}

__global__ void k_block_sums_all(Batch9 A, int* __restrict__ bsum_all) {
    const MatB mm = A.m[blockIdx.y];
    int* bsum = bsum_all + blockIdx.y * 256;
    int n = mm.nrows;
    int t = threadIdx.x;
    int g0 = blockIdx.x * 1024 + t * 4;
    int s = 0;
#pragma unroll
    for (int k = 0; k < 4; ++k) if (g0 + k < n) s += mm.rp[g0 + k];
#pragma unroll
    for (int off = 32; off; off >>= 1) s += __shfl_down(s, off, 64);
    __shared__ int ws_[4];
    if ((t & 63) == 0) ws_[t >> 6] = s;
    __syncthreads();
    if (t == 0) bsum[blockIdx.x] = ws_[0] + ws_[1] + ws_[2] + ws_[3];
}

__global__ void k_scan_bsums_all(Batch9 A, int* __restrict__ bsum_all) {
    const MatB mm = A.m[blockIdx.y];
    int* bsum = bsum_all + blockIdx.y * 256;
    int nblk = (mm.nrows + 1023) / 1024;
    __shared__ int s[256];
    int t = threadIdx.x;
    int v = (t < nblk) ? bsum[t] : 0;
    s[t] = v;
    __syncthreads();
    for (int off = 1; off < 256; off <<= 1) {
        int x = (t >= off) ? s[t - off] : 0;
        __syncthreads();
        s[t] += x;
        __syncthreads();
    }
    if (t < nblk) bsum[t] = s[t] - v;
    if (t == 255) mm.rp[mm.nrows] = s[255];
}

__global__ void k_scan_chunk_all(Batch9 A, const int* __restrict__ bsum_all) {
    const MatB mm = A.m[blockIdx.y];
    const int* bsum = bsum_all + blockIdx.y * 256;
    int n = mm.nrows;
    int t = threadIdx.x;
    int g0 = blockIdx.x * 1024 + t * 4;
    int v0 = 0, v1 = 0, v2 = 0, v3 = 0;
    if (g0 + 0 < n) v0 = mm.rp[g0 + 0];
    if (g0 + 1 < n) v1 = mm.rp[g0 + 1];
    if (g0 + 2 < n) v2 = mm.rp[g0 + 2];
    if (g0 + 3 < n) v3 = mm.rp[g0 + 3];
    int local = v0 + v1 + v2 + v3;
    int lane = t & 63, w = t >> 6;
    int inc = local;
#pragma unroll
    for (int off = 1; off < 64; off <<= 1) {
        int o = __shfl_up(inc, off, 64);
        if (lane >= off) inc += o;
    }
    __shared__ int wsum[4];
    if (lane == 63) wsum[w] = inc;
    __syncthreads();
    int wbase = 0;
    for (int i = 0; i < w; ++i) wbase += wsum[i];
    int run = bsum[blockIdx.x] + wbase + (inc - local);
    if (g0 + 0 < n) { mm.rp[g0 + 0] = run; mm.cur[g0 + 0] = run; run += v0; }
    if (g0 + 1 < n) { mm.rp[g0 + 1] = run; mm.cur[g0 + 1] = run; run += v1; }
    if (g0 + 2 < n) { mm.rp[g0 + 2] = run; mm.cur[g0 + 2] = run; run += v2; }
    if (g0 + 3 < n) { mm.rp[g0 + 3] = run; mm.cur[g0 + 3] = run; run += v3; }
}

// =====================================================================
// two-pass bucketed scatter (U-matrices): bucket = row >> BSHIFT
// =====================================================================
__global__ void k_binit(const int* __restrict__ rp, int* __restrict__ bcur, int nb) {
    int i = blockIdx.x * blockDim.x + threadIdx.x;
    if (i < nb) bcur[i] = rp[i << BSHIFT];
}

// pass A: append 8B (row|col|q) to the row's bucket; frontier = nb lines (L2-hot)
__global__ void k_passA(const int* __restrict__ rows, const int* __restrict__ cols,
                        const float* __restrict__ vals, int nnz,
                        int* __restrict__ bcur, unsigned long long* __restrict__ stage) {
    int i = blockIdx.x * blockDim.x + threadIdx.x;
    if (i >= nnz) return;
    int r = rows[i];
    unsigned q = quant14(vals[i]);
    int p = atomicAdd(&bcur[r >> BSHIFT], 1);
    stage[p] = ((unsigned long long)(unsigned)r << 38) |
               ((unsigned long long)(unsigned)cols[i] << 14) | q;
}

// pass B: sequential read of bucket-grouped staging; exact-slot write stays
// inside the bucket's ~2.5KB pk region (L2-hit)
__global__ void k_passB(const unsigned long long* __restrict__ stage, int nnz,
                        int* __restrict__ cur, unsigned* __restrict__ pk) {
    int i = blockIdx.x * blockDim.x + threadIdx.x;
    if (i >= nnz) return;
    unsigned long long e = stage[i];
    int r = (int)(e >> 38);
    int p = atomicAdd(&cur[r], 1);
    pk[p] = (unsigned)e;            // low 32 bits = col<<14 | q
}

// direct scatter for small-row-count matrices (L, A): frontier L2-resident
__global__ void k_scatter_one(const int* __restrict__ rows, const int* __restrict__ cols,
                              const float* __restrict__ vals, int nnz,
                              int* __restrict__ cur, unsigned* __restrict__ pk) {
    int i = blockIdx.x * blockDim.x + threadIdx.x;
    if (i >= nnz) return;
    int p = atomicAdd(&cur[rows[i]], 1);
    pk[p] = ((unsigned)cols[i] << 14) | quant14(vals[i]);
}

// =====================================================================
// mega: 4 packed-CSR row-sums + attention fusion; one user per 32-lane group
// =====================================================================
__global__ void k_mega(const int* __restrict__ rp0, const unsigned* __restrict__ pk0,
                       const int* __restrict__ rp1, const unsigned* __restrict__ pk1,
                       const int* __restrict__ rp2, const unsigned* __restrict__ pk2,
                       const int* __restrict__ rp3, const unsigned* __restrict__ pk3,
                       const unsigned short* __restrict__ x,
                       const float* __restrict__ W1, const float* __restrict__ b1,
                       const float* __restrict__ w2,
                       unsigned short* __restrict__ u_out, float* __restrict__ out_users, int f) {
    __shared__ float sW[32 * 32];
    __shared__ float sb[32];
    __shared__ float sw2[32];
    for (int i = threadIdx.x; i < 1024; i += blockDim.x) sW[i] = W1[i];
    if (threadIdx.x < 32) { sb[threadIdx.x] = b1[threadIdx.x]; sw2[threadIdx.x] = w2[threadIdx.x]; }
    __syncthreads();

    int grp = threadIdx.x >> 5;
    int lane = threadIdx.x & 31;
    int r = blockIdx.x * 8 + grp;
    if (r >= U_N) return;

    const int*      rps[4] = {rp0, rp1, rp2, rp3};
    const unsigned* pks[4] = {pk0, pk1, pk2, pk3};
    float zk[4];
#pragma unroll 1
    for (int ch = 0; ch < 4; ++ch) {
        const int* rp = rps[ch];
        const unsigned* pk = pks[ch];
        int j = rp[r], end = rp[r + 1];
        float a = 0.f;
        for (; j + 8 <= end; j += 8) {
            unsigned e0 = pk[j],     e1 = pk[j + 1], e2 = pk[j + 2], e3 = pk[j + 3];
            unsigned e4 = pk[j + 4], e5 = pk[j + 5], e6 = pk[j + 6], e7 = pk[j + 7];
            a += gfma(x, e0, lane); a += gfma(x, e1, lane);
            a += gfma(x, e2, lane); a += gfma(x, e3, lane);
            a += gfma(x, e4, lane); a += gfma(x, e5, lane);
            a += gfma(x, e6, lane); a += gfma(x, e7, lane);
        }
        for (; j + 4 <= end; j += 4) {
            unsigned e0 = pk[j], e1 = pk[j + 1], e2 = pk[j + 2], e3 = pk[j + 3];
            a += gfma(x, e0, lane); a += gfma(x, e1, lane);
            a += gfma(x, e2, lane); a += gfma(x, e3, lane);
        }
        for (; j < end; ++j) a += gfma(x, pk[j], lane);
        zk[ch] = a;
    }

    float w[4];
#pragma unroll
    for (int k = 0; k < 4; ++k) {
        float h = sb[lane];
#pragma unroll
        for (int i = 0; i < 32; ++i) {
            float zi = __shfl(zk[k], i, 32);
            h += zi * sW[i * 32 + lane];
        }
        float p = tanhf(h) * sw2[lane];
#pragma unroll
        for (int off = 16; off; off >>= 1) p += __shfl_xor(p, off, 32);
        w[k] = p;
    }
    float m = fmaxf(fmaxf(w[0], w[1]), fmaxf(w[2], w[3]));
    float e0 = __expf(w[0] - m), e1 = __expf(w[1] - m), e2 = __expf(w[2] - m), e3 = __expf(w[3] - m);
    float inv = 1.f / (e0 + e1 + e2 + e3);
    float o = (e0 * zk[0] + e1 * zk[1] + e2 * zk[2] + e3 * zk[3]) * inv;
    u_out[(size_t)r * 32 + lane] = f2bf(o);
    out_users[(size_t)r * 96 + f * 32 + lane] += o;
}

// =====================================================================
// vtoe kernels
// =====================================================================
__global__ void k_vtoe_split(const int* __restrict__ rp, const unsigned* __restrict__ pk,
                             const unsigned short* __restrict__ x, float* __restrict__ out,
                             int n_rows, int S) {
    int gid = (blockIdx.x * blockDim.x + threadIdx.x) >> 5;
    int lane = threadIdx.x & 31;
    if (gid >= n_rows * S) return;
    int r = gid / S, s = gid - r * S;
    int beg = rp[r], end = rp[r + 1], len = end - beg;
    int chunk = (len + S - 1) / S;
    int b = beg + s * chunk;
    int e = min(end, b + chunk);
    if (b >= e) return;
    float a = 0.f;
    int j = b;
    for (; j + 4 <= e; j += 4) {
        unsigned t0 = pk[j], t1 = pk[j + 1], t2 = pk[j + 2], t3 = pk[j + 3];
        a += gfma(x, t0, lane); a += gfma(x, t1, lane);
        a += gfma(x, t2, lane); a += gfma(x, t3, lane);
    }
    for (; j < e; ++j) a += gfma(x, pk[j], lane);
    atomicAdd(&out[(size_t)r * 32 + lane], a);
}

// T=48 rows: LDS accumulate per block from raw COO, atomic flush
__global__ void k_spmm_smallT_bf16(const int* __restrict__ rows, const int* __restrict__ cols,
                                   const float* __restrict__ vals, int nnz,
                                   const unsigned short* __restrict__ x, float* __restrict__ y) {
    __shared__ float acc[T_N * 32];
    for (int i = threadIdx.x; i < T_N * 32; i += blockDim.x) acc[i] = 0.f;
    __syncthreads();
    int d = threadIdx.x & 31;
    int grp = threadIdx.x >> 5;
    int per_block = (nnz + gridDim.x - 1) / gridDim.x;
    int start = blockIdx.x * per_block;
    int end = min(nnz, start + per_block);
    for (int nz = start + grp; nz < end; nz += (blockDim.x >> 5))
        atomicAdd(&acc[rows[nz] * 32 + d],
                  vals[nz] * bf2f(x[((size_t)cols[nz] << 5) + d]));
    __syncthreads();
    for (int i = threadIdx.x; i < T_N * 32; i += blockDim.x)
        if (acc[i] != 0.f) atomicAdd(&y[i], acc[i]);
}

// =====================================================================
// fallback (atomic z) kernels — only used if ws is unexpectedly small
// =====================================================================
__global__ void k_init_users_f32(const float* __restrict__ ue,
                                 float* __restrict__ u_l, float* __restrict__ u_t,
                                 float* __restrict__ u_a, float* __restrict__ out_users) {
    int i = blockIdx.x * blockDim.x + threadIdx.x;
    if (i >= U_N * 96) return;
    float v = ue[i];
    out_users[i] = v;
    int u = i / 96;
    int d = i - u * 96;
    if (d < 32)       u_l[u * 32 + d]      = v;
    else if (d < 64)  u_t[u * 32 + d - 32] = v;
    else              u_a[u * 32 + d - 64] = v;
}

__global__ void k_spmm(const int* __restrict__ rows, const int* __restrict__ cols,
                       const float* __restrict__ vals, int nnz,
                       const float* __restrict__ x, float* __restrict__ y) {
    int tid = blockIdx.x * blockDim.x + threadIdx.x;
    int nz = tid >> 5;
    if (nz >= nnz) return;
    int d = tid & 31;
    atomicAdd(&y[(size_t)rows[nz] * 32 + d], vals[nz] * x[(size_t)cols[nz] * 32 + d]);
}

__global__ void k_spmm_smallT(const int* __restrict__ rows, const int* __restrict__ cols,
                              const float* __restrict__ vals, int nnz,
                              const float* __restrict__ x, float* __restrict__ y) {
    __shared__ float acc[T_N * 32];
    for (int i = threadIdx.x; i < T_N * 32; i += blockDim.x) acc[i] = 0.f;
    __syncthreads();
    int d = threadIdx.x & 31;
    int grp = threadIdx.x >> 5;
    int per_block = (nnz + gridDim.x - 1) / gridDim.x;
    int start = blockIdx.x * per_block;
    int end = min(nnz, start + per_block);
    for (int nz = start + grp; nz < end; nz += (blockDim.x >> 5))
        atomicAdd(&acc[rows[nz] * 32 + d], vals[nz] * x[(size_t)cols[nz] * 32 + d]);
    __syncthreads();
    for (int i = threadIdx.x; i < T_N * 32; i += blockDim.x)
        if (acc[i] != 0.f) atomicAdd(&y[i], acc[i]);
}

__global__ void k_attn(const float* __restrict__ z, const float* __restrict__ W1,
                       const float* __restrict__ b1, const float* __restrict__ w2,
                       float* __restrict__ u_out, float* __restrict__ out_users, int f) {
    __shared__ float sW[32 * 32];
    __shared__ float sb[32];
    __shared__ float sw2[32];
    for (int i = threadIdx.x; i < 1024; i += blockDim.x) sW[i] = W1[i];
    if (threadIdx.x < 32) { sb[threadIdx.x] = b1[threadIdx.x]; sw2[threadIdx.x] = w2[threadIdx.x]; }
    __syncthreads();
    int half = threadIdx.x >> 5;
    int j = threadIdx.x & 31;
    int u = blockIdx.x * 8 + half;
    if (u >= U_N) return;
    float zk[4];
#pragma unroll
    for (int k = 0; k < 4; ++k) zk[k] = z[(size_t)k * (U_N * 32) + (size_t)u * 32 + j];
    float w[4];
#pragma unroll
    for (int k = 0; k < 4; ++k) {
        float h = sb[j];
#pragma unroll
        for (int i = 0; i < 32; ++i) h += __shfl(zk[k], i, 32) * sW[i * 32 + j];
        float p = tanhf(h) * sw2[j];
#pragma unroll
        for (int off = 16; off; off >>= 1) p += __shfl_xor(p, off, 32);
        w[k] = p;
    }
    float m = fmaxf(fmaxf(w[0], w[1]), fmaxf(w[2], w[3]));
    float e0 = __expf(w[0] - m), e1 = __expf(w[1] - m), e2 = __expf(w[2] - m), e3 = __expf(w[3] - m);
    float inv = 1.f / (e0 + e1 + e2 + e3);
    float o = (e0 * zk[0] + e1 * zk[1] + e2 * zk[2] + e3 * zk[3]) * inv;
    u_out[(size_t)u * 32 + j] = o;
    out_users[(size_t)u * 96 + f * 32 + j] += o;
}

// =====================================================================
// host
// =====================================================================
extern "C" void kernel_launch(void* const* d_in, const int* in_sizes, int n_in,
                              void* d_out, int out_size, void* d_ws, size_t ws_size,
                              hipStream_t stream) {
    const float* user_emb = (const float*)d_in[0];
    const float* loc_emb  = (const float*)d_in[1];
    const float* time_emb = (const float*)d_in[2];
    const float* act_emb  = (const float*)d_in[3];
    const float* W1s[3] = {(const float*)d_in[4], (const float*)d_in[7], (const float*)d_in[10]};
    const float* b1s[3] = {(const float*)d_in[5], (const float*)d_in[8], (const float*)d_in[11]};
    const float* w2s[3] = {(const float*)d_in[6], (const float*)d_in[9], (const float*)d_in[12]};

    struct Mat { const int* r; const int* c; const float* v; int nnz; int nrows; };
    auto mk = [&](int base, int nrows) {
        return Mat{(const int*)d_in[base], (const int*)d_in[base + 1],
                   (const float*)d_in[base + 2], in_sizes[base], nrows};
    };
    // global ids: 0..6 L,T,A,LT,LA,TA,LTA (rows=U); 7 vtoeL; 8 vtoeT; 9 vtoeA
    Mat M[10] = {mk(13, U_N), mk(16, U_N), mk(19, U_N), mk(22, U_N), mk(25, U_N),
                 mk(28, U_N), mk(31, U_N), mk(34, L_N), mk(37, T_N), mk(40, A_N)};
    // batch slots (CSR-built): 0..6 = U-mats, 7 = vtoeL(gid 7), 8 = vtoeA(gid 9)
    const int g_of_b[9] = {0, 1, 2, 3, 4, 5, 6, 7, 9};

    float* out       = (float*)d_out;
    float* out_users = out;
    float* out_l     = out + (size_t)U_N * 96;
    float* out_t     = out_l + (size_t)L_N * 32;
    float* out_a     = out_t + (size_t)T_N * 32;

    const int chmat[3][4] = {{0, 3, 4, 6}, {1, 3, 5, 6}, {2, 4, 5, 6}};

    // ------- workspace layout (all resident) -------
    auto align256 = [](size_t x) { return (x + 255) & ~(size_t)255; };
    char* wsb = (char*)d_ws;
    size_t off = 0;
    size_t ubuf_off[4];
    for (int b = 0; b < 4; ++b) { ubuf_off[b] = off; off = align256(off + (size_t)U_N * 32 * 2); }
    size_t rp_off[9], cur_off[9], pk_off[9];
    size_t rp_begin = off;
    for (int b = 0; b < 9; ++b) { rp_off[b] = off; off = align256(off + ((size_t)M[g_of_b[b]].nrows + 1) * 4); }
    size_t rp_total = off - rp_begin;
    for (int b = 0; b < 9; ++b) { cur_off[b] = off; off = align256(off + ((size_t)M[g_of_b[b]].nrows + 1) * 4); }
    size_t bs_off = off; off = align256(off + 9 * 256 * 4);
    const int NBUCK = (U_N + (1 << BSHIFT) - 1) >> BSHIFT;
    size_t bc_off = off; off = align256(off + (size_t)NBUCK * 4);
    size_t max_u_nnz = 0;
    for (int b = 0; b < 7; ++b) if ((size_t)M[b].nnz > max_u_nnz) max_u_nnz = M[b].nnz;
    size_t stage_off = off; off = align256(off + max_u_nnz * 8);
    for (int b = 0; b < 9; ++b) { pk_off[b] = off; off = align256(off + (size_t)M[g_of_b[b]].nnz * 4); }
    size_t NEED = off;

    if (ws_size >= NEED) {
        // ======================= packed-CSR path =======================
        Batch9 A;
        int max_nnz = 0, max_nrows = 0;
        for (int b = 0; b < 9; ++b) {
            const Mat& mm = M[g_of_b[b]];
            A.m[b].r = mm.r; A.m[b].c = mm.c; A.m[b].v = mm.v;
            A.m[b].nnz = mm.nnz; A.m[b].nrows = mm.nrows;
            A.m[b].rp  = (int*)(wsb + rp_off[b]);
            A.m[b].cur = (int*)(wsb + cur_off[b]);
            A.m[b].pk  = (unsigned*)(wsb + pk_off[b]);
            if (mm.nnz > max_nnz) max_nnz = mm.nnz;
            if (mm.nrows > max_nrows) max_nrows = mm.nrows;
        }
        int* bsum_all = (int*)(wsb + bs_off);
        int* bcur = (int*)(wsb + bc_off);
        unsigned long long* stage = (unsigned long long*)(wsb + stage_off);

        hipMemsetAsync(wsb + rp_begin, 0, rp_total, stream);
        dim3 gh((max_nnz + 255) / 256, 9);
        dim3 gb((max_nrows + 1023) / 1024, 9);
        k_hist_all<<<gh, 256, 0, stream>>>(A);
        k_block_sums_all<<<gb, 256, 0, stream>>>(A, bsum_all);
        k_scan_bsums_all<<<dim3(1, 9), 256, 0, stream>>>(A, bsum_all);
        k_scan_chunk_all<<<gb, 256, 0, stream>>>(A, bsum_all);

        // U-matrices: two-pass bucketed scatter (staging reused sequentially)
        for (int b = 0; b < 7; ++b) {
            const Mat& mm = M[b];
            k_binit<<<(NBUCK + 255) / 256, 256, 0, stream>>>(A.m[b].rp, bcur, NBUCK);
            k_passA<<<(mm.nnz + 255) / 256, 256, 0, stream>>>(
                mm.r, mm.c, mm.v, mm.nnz, bcur, stage);
            k_passB<<<(mm.nnz + 255) / 256, 256, 0, stream>>>(
                stage, mm.nnz, A.m[b].cur, A.m[b].pk);
        }
        // vtoeL / vtoeA: direct scatter (small frontier)
        for (int b = 7; b < 9; ++b) {
            const Mat& mm = M[g_of_b[b]];
            k_scatter_one<<<(mm.nnz + 255) / 256, 256, 0, stream>>>(
                mm.r, mm.c, mm.v, mm.nnz, A.m[b].cur, A.m[b].pk);
        }

        // ---- init snapshots
        unsigned short* bufs[4];
        for (int b = 0; b < 4; ++b) bufs[b] = (unsigned short*)(wsb + ubuf_off[b]);
        unsigned short* ucur[3] = {bufs[0], bufs[1], bufs[2]};
        unsigned short* uspare = bufs[3];
        k_init_users<<<(U_N * 96 + 255) / 256, 256, 0, stream>>>(
            user_emb, ucur[0], ucur[1], ucur[2], out_users);
        hipMemcpyAsync(out_l, loc_emb,  (size_t)L_N * 32 * 4, hipMemcpyDeviceToDevice, stream);
        hipMemcpyAsync(out_t, time_emb, (size_t)T_N * 32 * 4, hipMemcpyDeviceToDevice, stream);
        hipMemcpyAsync(out_a, act_emb,  (size_t)A_N * 32 * 4, hipMemcpyDeviceToDevice, stream);

        // ---- factor-major main loops
        for (int f = 0; f < 3; ++f) {
            const int* cm = chmat[f];
            for (int layer = 0; layer < 2; ++layer) {
                // vertex->edge from pre-attention ucur[f]
                if (f == 0) {
                    int ngrp = L_N * 4;
                    k_vtoe_split<<<((size_t)ngrp * 32 + 255) / 256, 256, 0, stream>>>(
                        A.m[7].rp, A.m[7].pk, ucur[0], out_l, L_N, 4);
                } else if (f == 1) {
                    k_spmm_smallT_bf16<<<2048, 256, 0, stream>>>(
                        M[8].r, M[8].c, M[8].v, M[8].nnz, ucur[1], out_t);
                } else {
                    int ngrp = A_N * 16;
                    k_vtoe_split<<<((size_t)ngrp * 32 + 255) / 256, 256, 0, stream>>>(
                        A.m[8].rp, A.m[8].pk, ucur[2], out_a, A_N, 16);
                }
                // fused 4-channel pull-spmm + attention
                k_mega<<<(U_N + 7) / 8, 256, 0, stream>>>(
                    A.m[cm[0]].rp, A.m[cm[0]].pk,
                    A.m[cm[1]].rp, A.m[cm[1]].pk,
                    A.m[cm[2]].rp, A.m[cm[2]].pk,
                    A.m[cm[3]].rp, A.m[cm[3]].pk,
                    ucur[f], W1s[f], b1s[f], w2s[f], uspare, out_users, f);
                unsigned short* t = ucur[f]; ucur[f] = uspare; uspare = t;
            }
        }
    } else {
        // ======================= atomic fallback =======================
        float* ws = (float*)d_ws;
        float* z = ws;
        float* u[3];
        u[0] = ws + (size_t)4 * U_N * 32;
        u[1] = u[0] + (size_t)U_N * 32;
        u[2] = u[1] + (size_t)U_N * 32;
        k_init_users_f32<<<(U_N * 96 + 255) / 256, 256, 0, stream>>>(
            user_emb, u[0], u[1], u[2], out_users);
        hipMemcpyAsync(out_l, loc_emb,  (size_t)L_N * 32 * 4, hipMemcpyDeviceToDevice, stream);
        hipMemcpyAsync(out_t, time_emb, (size_t)T_N * 32 * 4, hipMemcpyDeviceToDevice, stream);
        hipMemcpyAsync(out_a, act_emb,  (size_t)A_N * 32 * 4, hipMemcpyDeviceToDevice, stream);
        float* oute[3] = {out_l, out_t, out_a};
        for (int layer = 0; layer < 2; ++layer) {
            for (int f = 0; f < 3; ++f) {
                hipMemsetAsync(z, 0, (size_t)4 * U_N * 32 * 4, stream);
                for (int k = 0; k < 4; ++k) {
                    Mat& m = M[chmat[f][k]];
                    k_spmm<<<((size_t)m.nnz * 32 + 255) / 256, 256, 0, stream>>>(
                        m.r, m.c, m.v, m.nnz, u[f], z + (size_t)k * U_N * 32);
                }
                Mat& vm = M[7 + f];
                if (f == 1)
                    k_spmm_smallT<<<2048, 256, 0, stream>>>(vm.r, vm.c, vm.v, vm.nnz, u[f], oute[f]);
                else
                    k_spmm<<<((size_t)vm.nnz * 32 + 255) / 256, 256, 0, stream>>>(
                        vm.r, vm.c, vm.v, vm.nnz, u[f], oute[f]);
                k_attn<<<(U_N + 7) / 8, 256, 0, stream>>>(z, W1s[f], b1s[f], w2s[f], u[f], out_users, f);
            }
        }
    }

    int total = U_N * 96 + L_N * 32 + T_N * 32 + A_N * 32;
    k_scale<<<(total + 255) / 256, 256, 0, stream>>>(out, total);
}